// Round 1
// baseline (639.861 us; speedup 1.0000x reference)
//
#include <hip/hip_runtime.h>

typedef __attribute__((ext_vector_type(8))) short short8;
typedef __attribute__((ext_vector_type(4))) float f32x4;
typedef __attribute__((ext_vector_type(4))) unsigned short us4;

__device__ __forceinline__ unsigned short f2bf(float f) {
  unsigned u = __builtin_bit_cast(unsigned, f);
  u += 0x7FFFu + ((u >> 16) & 1u);
  return (unsigned short)(u >> 16);
}

__device__ __forceinline__ void gll16(const void* g, void* l) {
  __builtin_amdgcn_global_load_lds(
      (const __attribute__((address_space(1))) void*)g,
      (__attribute__((address_space(3))) void*)l, 16, 0, 0);
}

__device__ __forceinline__ f32x4 MFMA(short8 a, short8 b, f32x4 c) {
  return __builtin_amdgcn_mfma_f32_16x16x32_bf16(a, b, c, 0, 0, 0);
}

// ---------------- prep kernels ----------------

__global__ void conv_bf16(const float* __restrict__ in, unsigned short* __restrict__ out, int n4) {
  for (int i = blockIdx.x * blockDim.x + threadIdx.x; i < n4; i += gridDim.x * blockDim.x) {
    float4 v = ((const float4*)in)[i];
    us4 o;
    o[0] = f2bf(v.x); o[1] = f2bf(v.y); o[2] = f2bf(v.z); o[3] = f2bf(v.w);
    ((us4*)out)[i] = o;
  }
}

// in: fp32 [R][C] -> out: bf16 [C][R], scaled
__global__ void tconv(const float* __restrict__ in, unsigned short* __restrict__ out,
                      int R, int C, float scale) {
  __shared__ float tile[32][33];
  int bx = blockIdx.x, by = blockIdx.y;
  int tx = threadIdx.x, ty = threadIdx.y;
#pragma unroll
  for (int i = 0; i < 4; ++i)
    tile[ty + i * 8][tx] = in[(long)(by * 32 + ty + i * 8) * C + bx * 32 + tx];
  __syncthreads();
#pragma unroll
  for (int i = 0; i < 4; ++i)
    out[(long)(bx * 32 + ty + i * 8) * R + by * 32 + tx] = f2bf(tile[tx][ty + i * 8] * scale);
}

// C[128][128] = A[128][64] @ B[64][128]   (fp32, tiny)
__global__ void fold_wc(const float* __restrict__ A, const float* __restrict__ Bm,
                        float* __restrict__ Cm) {
  int j = threadIdx.x;  // 128
  int m = blockIdx.x;   // 128
  float acc = 0.f;
#pragma unroll
  for (int l = 0; l < 64; ++l) acc += A[m * 64 + l] * Bm[l * 128 + j];
  Cm[m * 128 + j] = acc;
}

// We[k][h*128+j] = sum_m W[k][h*128+m] * Wc[m][j]
__global__ void make_eff(const float* __restrict__ W, const float* __restrict__ Wc,
                         float* __restrict__ We) {
  int j = threadIdx.x;  // 128
  int k = blockIdx.x;   // 2048
  int h = blockIdx.y;   // 4
  const float* wrow = W + (long)k * 512 + h * 128;
  float acc = 0.f;
#pragma unroll 8
  for (int m = 0; m < 128; ++m) acc += wrow[m] * Wc[m * 128 + j];
  We[(long)k * 512 + h * 128 + j] = acc;
}

// ---------------- GEMM: C[M][N] = A[M][K] @ BT[N][K]^T  (bf16 in, m97 structure) ----------------
// EPI 0: bf16 C row-major; 1: bf16 C transposed ([N][M]); 2: f32 C row-major
template <int EPI>
__global__ __launch_bounds__(256, 2) void gemm_bt(const unsigned short* __restrict__ A,
                                                  const unsigned short* __restrict__ BT,
                                                  void* __restrict__ Cout, int M, int N, int K) {
  __shared__ unsigned short As[128 * 32];
  __shared__ unsigned short Bs[128 * 32];
  const int tid = threadIdx.x;
  const int lane = tid & 63, w = tid >> 6;
  const int wr = w >> 1, wc = w & 1;
  const int c = lane & 15, hi = lane >> 4;
  const int nbn = N >> 7;
  const int bm = blockIdx.x / nbn, bn = blockIdx.x % nbn;
  const int row0 = bm << 7, col0 = bn << 7;

  const unsigned short* ga = A + (long)(row0 + (tid >> 2)) * K + ((tid & 3) << 3);
  const unsigned short* gb = BT + (long)(col0 + (tid >> 2)) * K + ((tid & 3) << 3);
  unsigned short* la = As + tid * 8;
  unsigned short* lb = Bs + tid * 8;
  const long sA = (long)64 * K;

  f32x4 acc[4][4] = {};

  for (int k0 = 0; k0 < K; k0 += 32) {
    __syncthreads();
    gll16(ga + k0, la);
    gll16(ga + sA + k0, la + 2048);
    gll16(gb + k0, lb);
    gll16(gb + sA + k0, lb + 2048);
    __syncthreads();
    short8 a[4], b[4];
#pragma unroll
    for (int m = 0; m < 4; ++m)
      a[m] = *(const short8*)&As[(wr * 64 + m * 16 + c) * 32 + hi * 8];
#pragma unroll
    for (int n = 0; n < 4; ++n)
      b[n] = *(const short8*)&Bs[(wc * 64 + n * 16 + c) * 32 + hi * 8];
#pragma unroll
    for (int m = 0; m < 4; ++m)
#pragma unroll
      for (int n = 0; n < 4; ++n) acc[m][n] = MFMA(a[m], b[n], acc[m][n]);
  }

  if (EPI == 0) {
    unsigned short* C = (unsigned short*)Cout;
#pragma unroll
    for (int m = 0; m < 4; ++m) {
      int r0 = row0 + wr * 64 + m * 16 + hi * 4;
#pragma unroll
      for (int n = 0; n < 4; ++n) {
        int cc = col0 + wc * 64 + n * 16 + c;
#pragma unroll
        for (int j = 0; j < 4; ++j) C[(long)(r0 + j) * N + cc] = f2bf(acc[m][n][j]);
      }
    }
  } else if (EPI == 1) {
    unsigned short* C = (unsigned short*)Cout;  // [N][M]
#pragma unroll
    for (int m = 0; m < 4; ++m) {
      int r0 = row0 + wr * 64 + m * 16 + hi * 4;
#pragma unroll
      for (int n = 0; n < 4; ++n) {
        int cc = col0 + wc * 64 + n * 16 + c;
        us4 v;
#pragma unroll
        for (int j = 0; j < 4; ++j) v[j] = f2bf(acc[m][n][j]);
        *(us4*)&C[(long)cc * M + r0] = v;
      }
    }
  } else {
    float* C = (float*)Cout;
#pragma unroll
    for (int m = 0; m < 4; ++m) {
      int r0 = row0 + wr * 64 + m * 16 + hi * 4;
#pragma unroll
      for (int n = 0; n < 4; ++n) {
        int cc = col0 + wc * 64 + n * 16 + c;
#pragma unroll
        for (int j = 0; j < 4; ++j) C[(long)(r0 + j) * N + cc] = acc[m][n][j];
      }
    }
  }
}

// ---------------- attention ----------------
// Q: [8192][2048] bf16 (pre-scaled by 1/sqrt(128)); Kr: [8192][512]; VT: [512][8192]
// out CTX: [8192][2048] bf16. grid (T/64=32, H=16, B=4), 256 threads (4 waves x 16 q-rows).
__global__ __launch_bounds__(256, 2) void attn_kernel(const unsigned short* __restrict__ Q,
                                                      const unsigned short* __restrict__ Kr,
                                                      const unsigned short* __restrict__ VT,
                                                      unsigned short* __restrict__ CTX) {
  const int qt = blockIdx.x, h = blockIdx.y, b = blockIdx.z;
  const int kvh = h >> 2;
  const int tid = threadIdx.x, lane = tid & 63, w = tid >> 6;
  const int c = lane & 15, hi = lane >> 4;

  __shared__ unsigned short Ks[64 * 128];   // [key][d], XOR-swizzled
  __shared__ unsigned short Vs[128 * 64];   // [d][key], XOR-swizzled
  __shared__ unsigned short Ps[4][16 * 72]; // per-wave P, padded stride 72

  const long qrow = (long)(b * 2048 + qt * 64 + w * 16 + c);
  short8 aq[4];
#pragma unroll
  for (int kk = 0; kk < 4; ++kk)
    aq[kk] = *(const short8*)&Q[qrow * 2048 + h * 128 + kk * 32 + hi * 8];

  f32x4 acc[8] = {};
  float mrow[4] = {-1e30f, -1e30f, -1e30f, -1e30f};
  float lrow[4] = {0.f, 0.f, 0.f, 0.f};

  const unsigned short* kbase = Kr + (long)b * 2048 * 512 + kvh * 128;
  const unsigned short* vbase = VT + (long)kvh * 128 * 8192 + b * 2048;

  for (int k0 = 0; k0 < 2048; k0 += 64) {
    __syncthreads();
#pragma unroll
    for (int i = 0; i < 4; ++i) {  // K tile: 64x128 bf16, linear LDS, pre-swizzled source
      int p = i * 4096 + tid * 16;
      int key = p >> 8;
      int d0 = ((p & 255) ^ ((key & 7) << 4)) >> 1;
      gll16(kbase + (long)(k0 + key) * 512 + d0, (char*)Ks + p);
    }
#pragma unroll
    for (int i = 0; i < 4; ++i) {  // V^T tile: 128x64
      int p = i * 4096 + tid * 16;
      int d = p >> 7;
      int key0 = ((p & 127) ^ ((d & 7) << 4)) >> 1;
      gll16(vbase + (long)d * 8192 + k0 + key0, (char*)Vs + p);
    }
    __syncthreads();

    // S = Q K^T  (16 q-rows x 64 keys per wave)
    f32x4 s[4] = {};
#pragma unroll
    for (int n = 0; n < 4; ++n) {
      int r = n * 16 + c;
#pragma unroll
      for (int kk = 0; kk < 4; ++kk) {
        int lb = r * 256 + (kk * 32 + hi * 8) * 2;
        int sb = lb ^ ((r & 7) << 4);
        short8 bk = *(const short8*)((const char*)Ks + sb);
        s[n] = MFMA(aq[kk], bk, s[n]);
      }
    }

    // online softmax (wave-parallel: 16-lane groups share a q-row)
    float pv[4][4];
#pragma unroll
    for (int j = 0; j < 4; ++j) {
      float t = fmaxf(fmaxf(s[0][j], s[1][j]), fmaxf(s[2][j], s[3][j]));
      t = fmaxf(t, __shfl_xor(t, 1));
      t = fmaxf(t, __shfl_xor(t, 2));
      t = fmaxf(t, __shfl_xor(t, 4));
      t = fmaxf(t, __shfl_xor(t, 8));
      float mn = fmaxf(mrow[j], t);
      float sc = __expf(mrow[j] - mn);
      mrow[j] = mn;
      float ps = 0.f;
#pragma unroll
      for (int n = 0; n < 4; ++n) {
        float e = __expf(s[n][j] - mn);
        pv[n][j] = e;
        ps += e;
      }
      ps += __shfl_xor(ps, 1);
      ps += __shfl_xor(ps, 2);
      ps += __shfl_xor(ps, 4);
      ps += __shfl_xor(ps, 8);
      lrow[j] = lrow[j] * sc + ps;
#pragma unroll
      for (int n8 = 0; n8 < 8; ++n8) acc[n8][j] *= sc;
    }

    // P -> LDS (per-wave region, padded), re-read in A-fragment layout
#pragma unroll
    for (int n = 0; n < 4; ++n)
#pragma unroll
      for (int j = 0; j < 4; ++j)
        Ps[w][(hi * 4 + j) * 72 + n * 16 + c] = f2bf(pv[n][j]);

    short8 ap[2];
#pragma unroll
    for (int kk = 0; kk < 2; ++kk)
      ap[kk] = *(const short8*)&Ps[w][c * 72 + kk * 32 + hi * 8];

    // ctx += P V
#pragma unroll
    for (int n = 0; n < 8; ++n) {
      int r = n * 16 + c;
#pragma unroll
      for (int kk = 0; kk < 2; ++kk) {
        int lb = r * 128 + (kk * 32 + hi * 8) * 2;
        int sb = lb ^ ((r & 7) << 4);
        short8 bv = *(const short8*)((const char*)Vs + sb);
        acc[n] = MFMA(ap[kk], bv, acc[n]);
      }
    }
  }

#pragma unroll
  for (int j = 0; j < 4; ++j) {
    float inv = 1.0f / lrow[j];
    long r = (long)(b * 2048 + qt * 64 + w * 16 + hi * 4 + j);
#pragma unroll
    for (int n = 0; n < 8; ++n)
      CTX[r * 2048 + h * 128 + n * 16 + c] = f2bf(acc[n][j] * inv);
  }
}

// ---------------- launch ----------------

extern "C" void kernel_launch(void* const* d_in, const int* in_sizes, int n_in, void* d_out,
                              int out_size, void* d_ws, size_t ws_size, hipStream_t stream) {
  (void)in_sizes; (void)n_in; (void)out_size; (void)ws_size;
  const float* x    = (const float*)d_in[0];
  const float* W_q  = (const float*)d_in[1];
  const float* W_k  = (const float*)d_in[2];
  const float* W_v  = (const float*)d_in[3];
  const float* Wk2l = (const float*)d_in[4];
  const float* Wv2l = (const float*)d_in[5];
  const float* Wkfl = (const float*)d_in[6];
  const float* Wvfl = (const float*)d_in[7];
  const float* W_o  = (const float*)d_in[8];
  float* out = (float*)d_out;

  char* ws = (char*)d_ws;
  unsigned short* Xb   = (unsigned short*)(ws + 0);          // 32 MiB (reused as CTXb)
  unsigned short* Qb   = (unsigned short*)(ws + 33554432);   // 32 MiB
  unsigned short* KRb  = (unsigned short*)(ws + 67108864);   // 8 MiB
  unsigned short* VTb  = (unsigned short*)(ws + 75497472);   // 8 MiB
  unsigned short* WqT  = (unsigned short*)(ws + 83886080);   // 8 MiB
  unsigned short* WoT  = (unsigned short*)(ws + 92274688);   // 8 MiB
  unsigned short* WkeT = (unsigned short*)(ws + 100663296);  // 2 MiB
  unsigned short* WveT = (unsigned short*)(ws + 102760448);  // 2 MiB
  float* Wkc    = (float*)(ws + 104857600);                  // 64 KiB
  float* Wvc    = (float*)(ws + 104923136);                  // 64 KiB
  float* Wstage = (float*)(ws + 104988672);                  // 4 MiB
  unsigned short* CTXb = Xb;

  // dtype conversion + weight folding
  conv_bf16<<<2048, 256, 0, stream>>>(x, Xb, 16777216 / 4);
  tconv<<<dim3(64, 64), dim3(32, 8), 0, stream>>>(W_q, WqT, 2048, 2048, 0.088388347648318447f);
  tconv<<<dim3(64, 64), dim3(32, 8), 0, stream>>>(W_o, WoT, 2048, 2048, 1.0f);
  fold_wc<<<128, 128, 0, stream>>>(Wk2l, Wkfl, Wkc);
  fold_wc<<<128, 128, 0, stream>>>(Wv2l, Wvfl, Wvc);
  make_eff<<<dim3(2048, 4), 128, 0, stream>>>(W_k, Wkc, Wstage);
  tconv<<<dim3(16, 64), dim3(32, 8), 0, stream>>>(Wstage, WkeT, 2048, 512, 1.0f);
  make_eff<<<dim3(2048, 4), 128, 0, stream>>>(W_v, Wvc, Wstage);
  tconv<<<dim3(16, 64), dim3(32, 8), 0, stream>>>(Wstage, WveT, 2048, 512, 1.0f);

  // projections (W_q pre-scaled by 1/sqrt(Dh))
  gemm_bt<0><<<1024, 256, 0, stream>>>(Xb, WqT, Qb, 8192, 2048, 2048);
  gemm_bt<0><<<256, 256, 0, stream>>>(Xb, WkeT, KRb, 8192, 512, 2048);
  gemm_bt<1><<<256, 256, 0, stream>>>(Xb, WveT, VTb, 8192, 512, 2048);  // V stored transposed

  // attention
  attn_kernel<<<dim3(32, 16, 4), 256, 0, stream>>>(Qb, KRb, VTb, CTXb);

  // output projection -> fp32 d_out
  gemm_bt<2><<<1024, 256, 0, stream>>>(CTXb, WoT, out, 8192, 2048, 2048);
}